// Round 1
// baseline (323.391 us; speedup 1.0000x reference)
//
#include <hip/hip_runtime.h>

// N=65536, D_IN=1024, D_LAT=128, K=512
#define NROWS 65536
#define DIN   1024
#define DLAT  128
#define KC    512

typedef __attribute__((ext_vector_type(8))) short bf16x8;
typedef __attribute__((ext_vector_type(4))) float f32x4;

__device__ inline short f2bf(float f) {
    unsigned u = __float_as_uint(f);
    return (short)((u + 0x7FFFu + ((u >> 16) & 1u)) >> 16);  // RNE f32->bf16
}

// ---------- prep: Wt[n][k] = bf16(W[k][n]); cb = bf16(centroids) ----------
__global__ __launch_bounds__(256) void prep_convert(const float* __restrict__ W,
                                                    const float* __restrict__ C,
                                                    short* __restrict__ Wt,
                                                    short* __restrict__ cb) {
    int idx = blockIdx.x * 256 + threadIdx.x;
    if (idx < DLAT * DIN) {                 // 131072 elements of Wt
        int n = idx >> 10, k = idx & 1023;  // Wt[n][k] = W[k][n]
        Wt[idx] = f2bf(W[k * DLAT + n]);
    } else {
        int i2 = idx - DLAT * DIN;
        if (i2 < KC * DLAT) cb[i2] = f2bf(C[i2]);
    }
}

// ---------- prep: csq[k] = ||centroid_k||^2 ----------
__global__ __launch_bounds__(64) void prep_csq(const float* __restrict__ C,
                                               float* __restrict__ csq) {
    int row = blockIdx.x;
    int lane = threadIdx.x;  // 0..63
    float a = C[row * DLAT + lane];
    float b = C[row * DLAT + 64 + lane];
    float s = a * a + b * b;
    #pragma unroll
    for (int m = 32; m >= 1; m >>= 1) s += __shfl_xor(s, m, 64);
    if (lane == 0) csq[row] = s;
}

// ---------- K1: l = x @ W + b  (bf16 MFMA, f32 out) ----------
__global__ __launch_bounds__(256) void gemm1(const float* __restrict__ x,
                                             const short* __restrict__ Wt,
                                             const float* __restrict__ bias,
                                             float* __restrict__ lout) {
    const int wid = threadIdx.x >> 6, lane = threadIdx.x & 63;
    const int l16 = lane & 15, lhi = lane >> 4;
    const int row0 = blockIdx.x * 64 + wid * 16;   // wave's 16 rows

    f32x4 acc[8];
    #pragma unroll
    for (int i = 0; i < 8; ++i) acc[i] = (f32x4){0.f, 0.f, 0.f, 0.f};

    const float* xrow = x + (long)(row0 + l16) * DIN;
    for (int k = 0; k < DIN; k += 32) {
        const float4* xp = (const float4*)(xrow + k + lhi * 8);
        float4 a0 = xp[0], a1 = xp[1];
        bf16x8 af;
        af[0] = f2bf(a0.x); af[1] = f2bf(a0.y); af[2] = f2bf(a0.z); af[3] = f2bf(a0.w);
        af[4] = f2bf(a1.x); af[5] = f2bf(a1.y); af[6] = f2bf(a1.z); af[7] = f2bf(a1.w);
        #pragma unroll
        for (int nb = 0; nb < 8; ++nb) {
            const bf16x8 bf = *(const bf16x8*)(Wt + (nb * 16 + l16) * DIN + k + lhi * 8);
            acc[nb] = __builtin_amdgcn_mfma_f32_16x16x32_bf16(af, bf, acc[nb], 0, 0, 0);
        }
    }
    #pragma unroll
    for (int nb = 0; nb < 8; ++nb) {
        int col = nb * 16 + l16;
        float bv = bias[col];
        #pragma unroll
        for (int r = 0; r < 4; ++r) {
            int row = row0 + lhi * 4 + r;   // C/D: col=lane&15, row=(lane>>4)*4+reg
            lout[(long)row * DLAT + col] = acc[nb][r] + bv;
        }
    }
}

// ---------- K2: S = l @ c^T; D; num=1/(1+D); Q=num/rowsum; Fq partials ----------
__global__ __launch_bounds__(256, 1) void gemm2_q(const float* __restrict__ lout,
                                                  const short* __restrict__ cb,
                                                  const float* __restrict__ csq,
                                                  float* __restrict__ Qout,
                                                  float* __restrict__ partial) {
    const int wid = threadIdx.x >> 6, lane = threadIdx.x & 63;
    const int l16 = lane & 15, lhi = lane >> 4;
    const int row0 = blockIdx.x * 64 + wid * 16;

    // A fragments (l rows, bf16) + per-row ||l||^2 in f32
    bf16x8 af[4];
    float sq = 0.f;
    const float* lrow = lout + (long)(row0 + l16) * DLAT;
    #pragma unroll
    for (int ks = 0; ks < 4; ++ks) {
        const float4* lp = (const float4*)(lrow + ks * 32 + lhi * 8);
        float4 v0 = lp[0], v1 = lp[1];
        sq += v0.x * v0.x + v0.y * v0.y + v0.z * v0.z + v0.w * v0.w
            + v1.x * v1.x + v1.y * v1.y + v1.z * v1.z + v1.w * v1.w;
        bf16x8 a;
        a[0] = f2bf(v0.x); a[1] = f2bf(v0.y); a[2] = f2bf(v0.z); a[3] = f2bf(v0.w);
        a[4] = f2bf(v1.x); a[5] = f2bf(v1.y); a[6] = f2bf(v1.z); a[7] = f2bf(v1.w);
        af[ks] = a;
    }
    sq += __shfl_xor(sq, 16, 64);
    sq += __shfl_xor(sq, 32, 64);          // lane L holds lsq of row (L&15)
    float lsqr[4];
    #pragma unroll
    for (int r = 0; r < 4; ++r) lsqr[r] = __shfl(sq, lhi * 4 + r, 64);

    f32x4 numv[32];
    float rsum[4] = {0.f, 0.f, 0.f, 0.f};
    #pragma unroll
    for (int nb = 0; nb < 32; ++nb) {
        f32x4 acc = (f32x4){0.f, 0.f, 0.f, 0.f};
        const short* cbase = cb + (nb * 16 + l16) * DLAT;
        #pragma unroll
        for (int ks = 0; ks < 4; ++ks) {
            const bf16x8 bf = *(const bf16x8*)(cbase + ks * 32 + lhi * 8);
            acc = __builtin_amdgcn_mfma_f32_16x16x32_bf16(af[ks], bf, acc, 0, 0, 0);
        }
        float cs = csq[nb * 16 + l16];
        f32x4 nm;
        #pragma unroll
        for (int r = 0; r < 4; ++r) {
            float Dv = lsqr[r] + cs - 2.f * acc[r];
            float v = 1.f / (1.f + Dv);    // alpha=1: (1+D)^(-1)
            nm[r] = v;
            rsum[r] += v;
        }
        numv[nb] = nm;
    }
    #pragma unroll
    for (int m = 1; m <= 8; m <<= 1) {
        #pragma unroll
        for (int r = 0; r < 4; ++r) rsum[r] += __shfl_xor(rsum[r], m, 64);
    }
    float inv[4];
    #pragma unroll
    for (int r = 0; r < 4; ++r) inv[r] = 1.f / rsum[r];

    __shared__ float lds_fq[4][KC];
    #pragma unroll
    for (int nb = 0; nb < 32; ++nb) {
        float cp = 0.f;
        #pragma unroll
        for (int r = 0; r < 4; ++r) {
            float q = numv[nb][r] * inv[r];
            Qout[(long)(row0 + lhi * 4 + r) * KC + nb * 16 + l16] = q;
            cp += q;
        }
        cp += __shfl_xor(cp, 16, 64);
        cp += __shfl_xor(cp, 32, 64);      // colsum over this wave's 16 rows
        if (lhi == 0) lds_fq[wid][nb * 16 + l16] = cp;
    }
    __syncthreads();
    for (int c = threadIdx.x; c < KC; c += 256) {
        partial[(long)blockIdx.x * KC + c] =
            lds_fq[0][c] + lds_fq[1][c] + lds_fq[2][c] + lds_fq[3][c];
    }
}

// ---------- K3: Fq[c] = sum over 1024 block partials (deterministic tree) ----------
__global__ __launch_bounds__(256) void fq_reduce(const float* __restrict__ partial,
                                                 float* __restrict__ fq) {
    int c = blockIdx.x;
    float s = 0.f;
    #pragma unroll
    for (int i = 0; i < 4; ++i) s += partial[(long)(threadIdx.x + i * 256) * KC + c];
    __shared__ float red[256];
    red[threadIdx.x] = s;
    __syncthreads();
    for (int off = 128; off >= 1; off >>= 1) {
        if (threadIdx.x < off) red[threadIdx.x] += red[threadIdx.x + off];
        __syncthreads();
    }
    if (threadIdx.x == 0) fq[c] = red[0];
}

// ---------- K4: P = rownorm(Q^2 / Fq) ----------
__global__ __launch_bounds__(256) void p_kernel(const float* __restrict__ Q,
                                                const float* __restrict__ fq,
                                                float* __restrict__ P) {
    const int wid = threadIdx.x >> 6, lane = threadIdx.x & 63;
    const int gw = blockIdx.x * 4 + wid;   // 0..8191 waves, each does 8 rows
    const float4 f0 = *(const float4*)(fq + lane * 8);
    const float4 f1 = *(const float4*)(fq + lane * 8 + 4);
    float inv[8] = {1.f / f0.x, 1.f / f0.y, 1.f / f0.z, 1.f / f0.w,
                    1.f / f1.x, 1.f / f1.y, 1.f / f1.z, 1.f / f1.w};
    for (int it = 0; it < 8; ++it) {
        const long row = gw + (long)it * 8192;
        const float4* qp = (const float4*)(Q + row * KC + lane * 8);
        float4 q0 = qp[0], q1 = qp[1];
        float n[8];
        n[0] = q0.x * q0.x * inv[0]; n[1] = q0.y * q0.y * inv[1];
        n[2] = q0.z * q0.z * inv[2]; n[3] = q0.w * q0.w * inv[3];
        n[4] = q1.x * q1.x * inv[4]; n[5] = q1.y * q1.y * inv[5];
        n[6] = q1.z * q1.z * inv[6]; n[7] = q1.w * q1.w * inv[7];
        float rs = n[0] + n[1] + n[2] + n[3] + n[4] + n[5] + n[6] + n[7];
        #pragma unroll
        for (int m = 1; m <= 32; m <<= 1) rs += __shfl_xor(rs, m, 64);
        float ir = 1.f / rs;
        float4 o0 = {n[0] * ir, n[1] * ir, n[2] * ir, n[3] * ir};
        float4 o1 = {n[4] * ir, n[5] * ir, n[6] * ir, n[7] * ir};
        float4* pp = (float4*)(P + row * KC + lane * 8);
        pp[0] = o0; pp[1] = o1;
    }
}

extern "C" void kernel_launch(void* const* d_in, const int* in_sizes, int n_in,
                              void* d_out, int out_size, void* d_ws, size_t ws_size,
                              hipStream_t stream) {
    const float* x  = (const float*)d_in[0];
    const float* W  = (const float*)d_in[1];
    const float* b  = (const float*)d_in[2];
    const float* C  = (const float*)d_in[3];

    float* out  = (float*)d_out;
    float* lout = out;                                   // 65536*128
    float* Qout = out + (long)NROWS * DLAT;              // 65536*512
    float* Pout = Qout + (long)NROWS * KC;               // 65536*512

    // workspace layout (needs ~2.44 MB)
    char*  ws      = (char*)d_ws;
    short* Wt      = (short*)ws;                         // 131072 * 2 B
    short* cb      = (short*)(ws + 262144);              // 65536 * 2 B
    float* csq     = (float*)(ws + 262144 + 131072);     // 512 * 4 B
    float* partial = (float*)(ws + 395264);              // 1024*512*4 = 2 MB
    float* fq      = (float*)(ws + 395264 + 2097152);    // 512 * 4 B

    hipLaunchKernelGGL(prep_convert, dim3(768),  dim3(256), 0, stream, W, C, Wt, cb);
    hipLaunchKernelGGL(prep_csq,     dim3(512),  dim3(64),  0, stream, C, csq);
    hipLaunchKernelGGL(gemm1,        dim3(1024), dim3(256), 0, stream, x, Wt, b, lout);
    hipLaunchKernelGGL(gemm2_q,      dim3(1024), dim3(256), 0, stream, lout, cb, csq, Qout, partial);
    hipLaunchKernelGGL(fq_reduce,    dim3(512),  dim3(256), 0, stream, partial, fq);
    hipLaunchKernelGGL(p_kernel,     dim3(2048), dim3(256), 0, stream, Qout, fq, Pout);
}

// Round 2
// 308.271 us; speedup vs baseline: 1.0490x; 1.0490x over previous
//
#include <hip/hip_runtime.h>

// N=65536, D_IN=1024, D_LAT=128, K=512
#define NROWS 65536
#define DIN   1024
#define DLAT  128
#define KC    512

typedef __attribute__((ext_vector_type(8))) short bf16x8;
typedef __attribute__((ext_vector_type(4))) float f32x4;

__device__ inline short f2bf(float f) {
    unsigned u = __float_as_uint(f);
    return (short)((u + 0x7FFFu + ((u >> 16) & 1u)) >> 16);  // RNE f32->bf16
}

// ---------- prep: Wt[n][k] = bf16(W[k][n]); cb = bf16(centroids) ----------
__global__ __launch_bounds__(256) void prep_convert(const float* __restrict__ W,
                                                    const float* __restrict__ C,
                                                    short* __restrict__ Wt,
                                                    short* __restrict__ cb) {
    int idx = blockIdx.x * 256 + threadIdx.x;
    if (idx < DLAT * DIN) {                 // 131072 elements of Wt
        int n = idx >> 10, k = idx & 1023;  // Wt[n][k] = W[k][n]
        Wt[idx] = f2bf(W[k * DLAT + n]);
    } else {
        int i2 = idx - DLAT * DIN;
        if (i2 < KC * DLAT) cb[i2] = f2bf(C[i2]);
    }
}

// ---------- prep: csq[k] = ||centroid_k||^2 ----------
__global__ __launch_bounds__(64) void prep_csq(const float* __restrict__ C,
                                               float* __restrict__ csq) {
    int row = blockIdx.x;
    int lane = threadIdx.x;  // 0..63
    float a = C[row * DLAT + lane];
    float b = C[row * DLAT + 64 + lane];
    float s = a * a + b * b;
    #pragma unroll
    for (int m = 32; m >= 1; m >>= 1) s += __shfl_xor(s, m, 64);
    if (lane == 0) csq[row] = s;
}

// ---------- K1: l = x @ W + b  (LDS-staged bf16 MFMA GEMM, BK=64) ----------
// Block: 256 thr / 4 waves, 64 rows. LDS: xs 16KB (f32, XOR-swz) + wlds 16KB (bf16, XOR-swz).
__global__ __launch_bounds__(256) void gemm1(const float* __restrict__ x,
                                             const short* __restrict__ Wt,
                                             const float* __restrict__ bias,
                                             float* __restrict__ lout) {
    __shared__ float xs[64 * 64];     // (row,col): addr4 = row*64 + ((col>>2)^(row&15))*4 + (col&3)
    __shared__ short wlds[128 * 64];  // (n,col):   addr2 = n*64 + (((col>>3)^(n&7))<<3) + (col&7)

    const int t = threadIdx.x;
    const int wid = t >> 6, lane = t & 63;
    const int l16 = lane & 15, lhi = lane >> 4;
    const int row0 = blockIdx.x * 64;

    // --- staging address precompute ---
    // x: thread t, j in 0..3: row = j*16 + (t>>4), cols (t&15)*4 .. +4   (256B contiguous per row)
    const float* xg = x + (long)(row0 + (t >> 4)) * DIN + (t & 15) * 4;
    const int xs_w = (t >> 4) * 64 + (((t & 15) ^ (t >> 4)) << 2);   // + j*16*64
    // Wt: thread t, j: n = j*32 + (t>>3), c8 = t&7  (16B slots)
    const short* wg = Wt + (long)(t >> 3) * DIN + (t & 7) * 8;
    const int ws_w = (t >> 3) * 64 + (((t & 7) ^ ((t >> 3) & 7)) << 3);  // + j*32*64

    f32x4 acc[8];
    #pragma unroll
    for (int i = 0; i < 8; ++i) acc[i] = (f32x4){0.f, 0.f, 0.f, 0.f};

    // prologue: load chunk 0 into regs
    float4 xr[4];
    bf16x8 wr[4];
    #pragma unroll
    for (int j = 0; j < 4; ++j) {
        xr[j] = *(const float4*)(xg + (long)j * 16 * DIN);
        wr[j] = *(const bf16x8*)(wg + (long)j * 32 * DIN);
    }

    for (int kc = 0; kc < 16; ++kc) {
        __syncthreads();   // previous chunk's consumers done
        #pragma unroll
        for (int j = 0; j < 4; ++j) {
            *(float4*)(xs + xs_w + j * 16 * 64) = xr[j];
            *(bf16x8*)(wlds + ws_w + j * 32 * 64) = wr[j];
        }
        __syncthreads();   // writes visible (compiler drains vm+lgkm here)

        // issue next chunk's loads now — latency hides under this chunk's compute
        if (kc < 15) {
            const int ko = (kc + 1) * 64;
            #pragma unroll
            for (int j = 0; j < 4; ++j) {
                xr[j] = *(const float4*)(xg + (long)j * 16 * DIN + ko);
                wr[j] = *(const bf16x8*)(wg + (long)j * 32 * DIN + ko);
            }
        }

        const int arow = wid * 16 + l16;
        #pragma unroll
        for (int ks = 0; ks < 2; ++ks) {
            // A fragment: 8 f32 from xs, two swizzled 16B slots, convert to bf16
            const int c4 = ks * 8 + lhi * 2;
            const float4 va0 = *(const float4*)(xs + arow * 64 + ((c4 ^ l16) << 2));
            const float4 va1 = *(const float4*)(xs + arow * 64 + (((c4 + 1) ^ l16) << 2));
            bf16x8 af;
            af[0] = f2bf(va0.x); af[1] = f2bf(va0.y); af[2] = f2bf(va0.z); af[3] = f2bf(va0.w);
            af[4] = f2bf(va1.x); af[5] = f2bf(va1.y); af[6] = f2bf(va1.z); af[7] = f2bf(va1.w);
            const int c8 = ks * 4 + lhi;
            #pragma unroll
            for (int nb = 0; nb < 8; ++nb) {
                const int n = nb * 16 + l16;
                const bf16x8 bf = *(const bf16x8*)(wlds + n * 64 + (((c8 ^ (n & 7))) << 3));
                acc[nb] = __builtin_amdgcn_mfma_f32_16x16x32_bf16(af, bf, acc[nb], 0, 0, 0);
            }
        }
    }

    #pragma unroll
    for (int nb = 0; nb < 8; ++nb) {
        int col = nb * 16 + l16;
        float bv = bias[col];
        #pragma unroll
        for (int r = 0; r < 4; ++r) {
            int row = row0 + wid * 16 + lhi * 4 + r;   // C/D: col=lane&15, row=(lane>>4)*4+reg
            lout[(long)row * DLAT + col] = acc[nb][r] + bv;
        }
    }
}

// ---------- K2: S = l @ c^T; D; num=1/(1+D); Q=num/rowsum; Fq partials ----------
__global__ __launch_bounds__(256, 1) void gemm2_q(const float* __restrict__ lout,
                                                  const short* __restrict__ cb,
                                                  const float* __restrict__ csq,
                                                  float* __restrict__ Qout,
                                                  float* __restrict__ partial) {
    const int wid = threadIdx.x >> 6, lane = threadIdx.x & 63;
    const int l16 = lane & 15, lhi = lane >> 4;
    const int row0 = blockIdx.x * 64 + wid * 16;

    // A fragments (l rows, bf16) + per-row ||l||^2 in f32
    bf16x8 af[4];
    float sq = 0.f;
    const float* lrow = lout + (long)(row0 + l16) * DLAT;
    #pragma unroll
    for (int ks = 0; ks < 4; ++ks) {
        const float4* lp = (const float4*)(lrow + ks * 32 + lhi * 8);
        float4 v0 = lp[0], v1 = lp[1];
        sq += v0.x * v0.x + v0.y * v0.y + v0.z * v0.z + v0.w * v0.w
            + v1.x * v1.x + v1.y * v1.y + v1.z * v1.z + v1.w * v1.w;
        bf16x8 a;
        a[0] = f2bf(v0.x); a[1] = f2bf(v0.y); a[2] = f2bf(v0.z); a[3] = f2bf(v0.w);
        a[4] = f2bf(v1.x); a[5] = f2bf(v1.y); a[6] = f2bf(v1.z); a[7] = f2bf(v1.w);
        af[ks] = a;
    }
    sq += __shfl_xor(sq, 16, 64);
    sq += __shfl_xor(sq, 32, 64);          // lane L holds lsq of row (L&15)
    float lsqr[4];
    #pragma unroll
    for (int r = 0; r < 4; ++r) lsqr[r] = __shfl(sq, lhi * 4 + r, 64);

    f32x4 numv[32];
    float rsum[4] = {0.f, 0.f, 0.f, 0.f};
    #pragma unroll
    for (int nb = 0; nb < 32; ++nb) {
        f32x4 acc = (f32x4){0.f, 0.f, 0.f, 0.f};
        const short* cbase = cb + (nb * 16 + l16) * DLAT;
        #pragma unroll
        for (int ks = 0; ks < 4; ++ks) {
            const bf16x8 bf = *(const bf16x8*)(cbase + ks * 32 + lhi * 8);
            acc = __builtin_amdgcn_mfma_f32_16x16x32_bf16(af[ks], bf, acc, 0, 0, 0);
        }
        float cs = csq[nb * 16 + l16];
        f32x4 nm;
        #pragma unroll
        for (int r = 0; r < 4; ++r) {
            float Dv = lsqr[r] + cs - 2.f * acc[r];
            float v = 1.f / (1.f + Dv);    // alpha=1: (1+D)^(-1)
            nm[r] = v;
            rsum[r] += v;
        }
        numv[nb] = nm;
    }
    #pragma unroll
    for (int m = 1; m <= 8; m <<= 1) {
        #pragma unroll
        for (int r = 0; r < 4; ++r) rsum[r] += __shfl_xor(rsum[r], m, 64);
    }
    float inv[4];
    #pragma unroll
    for (int r = 0; r < 4; ++r) inv[r] = 1.f / rsum[r];

    __shared__ float lds_fq[4][KC];
    #pragma unroll
    for (int nb = 0; nb < 32; ++nb) {
        float cp = 0.f;
        #pragma unroll
        for (int r = 0; r < 4; ++r) {
            float q = numv[nb][r] * inv[r];
            Qout[(long)(row0 + lhi * 4 + r) * KC + nb * 16 + l16] = q;
            cp += q;
        }
        cp += __shfl_xor(cp, 16, 64);
        cp += __shfl_xor(cp, 32, 64);      // colsum over this wave's 16 rows
        if (lhi == 0) lds_fq[wid][nb * 16 + l16] = cp;
    }
    __syncthreads();
    for (int c = threadIdx.x; c < KC; c += 256) {
        partial[(long)blockIdx.x * KC + c] =
            lds_fq[0][c] + lds_fq[1][c] + lds_fq[2][c] + lds_fq[3][c];
    }
}

// ---------- K3: Fq[c] = sum over 1024 block partials (deterministic tree) ----------
__global__ __launch_bounds__(256) void fq_reduce(const float* __restrict__ partial,
                                                 float* __restrict__ fq) {
    int c = blockIdx.x;
    float s = 0.f;
    #pragma unroll
    for (int i = 0; i < 4; ++i) s += partial[(long)(threadIdx.x + i * 256) * KC + c];
    __shared__ float red[256];
    red[threadIdx.x] = s;
    __syncthreads();
    for (int off = 128; off >= 1; off >>= 1) {
        if (threadIdx.x < off) red[threadIdx.x] += red[threadIdx.x + off];
        __syncthreads();
    }
    if (threadIdx.x == 0) fq[c] = red[0];
}

// ---------- K4: P = rownorm(Q^2 / Fq) ----------
__global__ __launch_bounds__(256) void p_kernel(const float* __restrict__ Q,
                                                const float* __restrict__ fq,
                                                float* __restrict__ P) {
    const int wid = threadIdx.x >> 6, lane = threadIdx.x & 63;
    const int gw = blockIdx.x * 4 + wid;   // 0..8191 waves, each does 8 rows
    const float4 f0 = *(const float4*)(fq + lane * 8);
    const float4 f1 = *(const float4*)(fq + lane * 8 + 4);
    float inv[8] = {1.f / f0.x, 1.f / f0.y, 1.f / f0.z, 1.f / f0.w,
                    1.f / f1.x, 1.f / f1.y, 1.f / f1.z, 1.f / f1.w};
    for (int it = 0; it < 8; ++it) {
        const long row = gw + (long)it * 8192;
        const float4* qp = (const float4*)(Q + row * KC + lane * 8);
        float4 q0 = qp[0], q1 = qp[1];
        float n[8];
        n[0] = q0.x * q0.x * inv[0]; n[1] = q0.y * q0.y * inv[1];
        n[2] = q0.z * q0.z * inv[2]; n[3] = q0.w * q0.w * inv[3];
        n[4] = q1.x * q1.x * inv[4]; n[5] = q1.y * q1.y * inv[5];
        n[6] = q1.z * q1.z * inv[6]; n[7] = q1.w * q1.w * inv[7];
        float rs = n[0] + n[1] + n[2] + n[3] + n[4] + n[5] + n[6] + n[7];
        #pragma unroll
        for (int m = 1; m <= 32; m <<= 1) rs += __shfl_xor(rs, m, 64);
        float ir = 1.f / rs;
        float4 o0 = {n[0] * ir, n[1] * ir, n[2] * ir, n[3] * ir};
        float4 o1 = {n[4] * ir, n[5] * ir, n[6] * ir, n[7] * ir};
        float4* pp = (float4*)(P + row * KC + lane * 8);
        pp[0] = o0; pp[1] = o1;
    }
}

extern "C" void kernel_launch(void* const* d_in, const int* in_sizes, int n_in,
                              void* d_out, int out_size, void* d_ws, size_t ws_size,
                              hipStream_t stream) {
    const float* x  = (const float*)d_in[0];
    const float* W  = (const float*)d_in[1];
    const float* b  = (const float*)d_in[2];
    const float* C  = (const float*)d_in[3];

    float* out  = (float*)d_out;
    float* lout = out;                                   // 65536*128
    float* Qout = out + (long)NROWS * DLAT;              // 65536*512
    float* Pout = Qout + (long)NROWS * KC;               // 65536*512

    // workspace layout (needs ~2.44 MB)
    char*  ws      = (char*)d_ws;
    short* Wt      = (short*)ws;                         // 131072 * 2 B
    short* cb      = (short*)(ws + 262144);              // 65536 * 2 B
    float* csq     = (float*)(ws + 262144 + 131072);     // 512 * 4 B
    float* partial = (float*)(ws + 395264);              // 1024*512*4 = 2 MB
    float* fq      = (float*)(ws + 395264 + 2097152);    // 512 * 4 B

    hipLaunchKernelGGL(prep_convert, dim3(768),  dim3(256), 0, stream, W, C, Wt, cb);
    hipLaunchKernelGGL(prep_csq,     dim3(512),  dim3(64),  0, stream, C, csq);
    hipLaunchKernelGGL(gemm1,        dim3(1024), dim3(256), 0, stream, x, Wt, b, lout);
    hipLaunchKernelGGL(gemm2_q,      dim3(1024), dim3(256), 0, stream, lout, cb, csq, Qout, partial);
    hipLaunchKernelGGL(fq_reduce,    dim3(512),  dim3(256), 0, stream, partial, fq);
    hipLaunchKernelGGL(p_kernel,     dim3(2048), dim3(256), 0, stream, Qout, fq, Pout);
}

// Round 3
// 242.369 us; speedup vs baseline: 1.3343x; 1.2719x over previous
//
#include <hip/hip_runtime.h>

// N=65536, D_IN=1024, D_LAT=128, K=512
#define NROWS 65536
#define DIN   1024
#define DLAT  128
#define KC    512

typedef __attribute__((ext_vector_type(8))) short bf16x8;
typedef __attribute__((ext_vector_type(4))) float f32x4;

// direct global->LDS DMA, 16B per lane, LDS dest = wave-uniform base + lane*16
#define GLDS16(gp, lp)                                                          \
    __builtin_amdgcn_global_load_lds((const __attribute__((address_space(1))) void*)(gp), \
                                     (__attribute__((address_space(3))) void*)(lp), 16, 0, 0)

__device__ inline short f2bf(float f) {
    unsigned u = __float_as_uint(f);
    return (short)((u + 0x7FFFu + ((u >> 16) & 1u)) >> 16);  // RNE f32->bf16
}

// ---------- prep: Wt[n][k] = bf16(W[k][n]); cb = bf16(centroids) ----------
__global__ __launch_bounds__(256) void prep_convert(const float* __restrict__ W,
                                                    const float* __restrict__ C,
                                                    short* __restrict__ Wt,
                                                    short* __restrict__ cb) {
    int idx = blockIdx.x * 256 + threadIdx.x;
    if (idx < DLAT * DIN) {                 // 131072 elements of Wt
        int n = idx >> 10, k = idx & 1023;  // Wt[n][k] = W[k][n]
        Wt[idx] = f2bf(W[k * DLAT + n]);
    } else {
        int i2 = idx - DLAT * DIN;
        if (i2 < KC * DLAT) cb[i2] = f2bf(C[i2]);
    }
}

// ---------- prep: csq[k] = ||centroid_k||^2 ----------
__global__ __launch_bounds__(64) void prep_csq(const float* __restrict__ C,
                                               float* __restrict__ csq) {
    int row = blockIdx.x;
    int lane = threadIdx.x;  // 0..63
    float a = C[row * DLAT + lane];
    float b = C[row * DLAT + 64 + lane];
    float s = a * a + b * b;
    #pragma unroll
    for (int m = 32; m >= 1; m >>= 1) s += __shfl_xor(s, m, 64);
    if (lane == 0) csq[row] = s;
}

// ---------- K1: l = x @ W + b  (global_load_lds staged bf16 MFMA GEMM, BK=64) ----------
// 256 thr / 4 waves, 64 rows/block. LDS 64KB: dbuf x (16KB f32) + W (16KB bf16), linear layout.
// Swizzle lives on the GLOBAL source address (m173 pattern); reads use the same involution.
__global__ __launch_bounds__(256) void gemm1(const float* __restrict__ x,
                                             const short* __restrict__ Wt,
                                             const float* __restrict__ bias,
                                             float* __restrict__ lout) {
    __shared__ char lds[65536];
    const int t = threadIdx.x;
    const int wid = t >> 6, lane = t & 63;
    const int l16 = lane & 15, lhi = lane >> 4;
    const int row0 = blockIdx.x * 64;

    // x: thread t stages row (t>>4)+j*16, 16B col-block ((t&15)^((t>>4)&15)) of the chunk
    const float* xsrc = x + (long)(row0 + (t >> 4)) * DIN + (((t & 15) ^ ((t >> 4) & 15)) << 2);
    // W: thread t stages n=(t>>3)+j*32, 16B col-block ((t&7)^((t>>3)&7)) of the chunk
    const short* wsrc = Wt + (long)(t >> 3) * DIN + (((t & 7) ^ ((t >> 3) & 7)) << 3);
    const int lofs = t * 16;   // linear LDS byte slot (matches HW lane*16 placement)

    f32x4 acc[8];
    #pragma unroll
    for (int i = 0; i < 8; ++i) acc[i] = (f32x4){0.f, 0.f, 0.f, 0.f};

    // prologue: stage chunk 0 into buffer 0
    {
        char* xb = lds;
        char* wb = lds + 16384;
        #pragma unroll
        for (int j = 0; j < 4; ++j) {
            GLDS16(xsrc + j * 16 * DIN, xb + lofs + j * 4096);
            GLDS16(wsrc + j * 32 * DIN, wb + lofs + j * 4096);
        }
    }
    __syncthreads();   // compiler drains vmcnt(0) before barrier -> chunk 0 landed

    int cur = 0;
    const int arow = wid * 16 + l16;
    for (int kc = 0; kc < 16; ++kc) {
        if (kc < 15) {   // issue next chunk's DMA; latency hides under this chunk's compute
            char* xb = lds + (cur ^ 1) * 32768;
            char* wb = xb + 16384;
            const float* xp = xsrc + (kc + 1) * 64;
            const short* wp = wsrc + (kc + 1) * 64;
            #pragma unroll
            for (int j = 0; j < 4; ++j) {
                GLDS16(xp + j * 16 * DIN, xb + lofs + j * 4096);
                GLDS16(wp + j * 32 * DIN, wb + lofs + j * 4096);
            }
        }
        const float* xs = (const float*)(lds + cur * 32768);
        const short* wl = (const short*)(lds + cur * 32768 + 16384);
        #pragma unroll
        for (int ks = 0; ks < 2; ++ks) {
            const int c4 = ks * 8 + lhi * 2;
            const float4 va0 = *(const float4*)(xs + arow * 64 + ((c4 ^ l16) << 2));
            const float4 va1 = *(const float4*)(xs + arow * 64 + (((c4 + 1) ^ l16) << 2));
            bf16x8 af;
            af[0] = f2bf(va0.x); af[1] = f2bf(va0.y); af[2] = f2bf(va0.z); af[3] = f2bf(va0.w);
            af[4] = f2bf(va1.x); af[5] = f2bf(va1.y); af[6] = f2bf(va1.z); af[7] = f2bf(va1.w);
            const int c8 = ks * 4 + lhi;
            #pragma unroll
            for (int nb = 0; nb < 8; ++nb) {
                const int n = nb * 16 + l16;
                const bf16x8 bf = *(const bf16x8*)(wl + n * 64 + ((c8 ^ (n & 7)) << 3));
                acc[nb] = __builtin_amdgcn_mfma_f32_16x16x32_bf16(af, bf, acc[nb], 0, 0, 0);
            }
        }
        __syncthreads();   // drains prefetch DMA (flew during compute) + ds reads
        cur ^= 1;
    }

    #pragma unroll
    for (int nb = 0; nb < 8; ++nb) {
        int col = nb * 16 + l16;
        float bv = bias[col];
        #pragma unroll
        for (int r = 0; r < 4; ++r) {
            int row = row0 + wid * 16 + lhi * 4 + r;   // C/D: col=lane&15, row=(lane>>4)*4+reg
            lout[(long)row * DLAT + col] = acc[nb][r] + bv;
        }
    }
}

// ---------- K2: S = l @ c^T; D; num=1/(1+D); Q=num/rowsum; Fq partials ----------
__global__ __launch_bounds__(256, 1) void gemm2_q(const float* __restrict__ lout,
                                                  const short* __restrict__ cb,
                                                  const float* __restrict__ csq,
                                                  float* __restrict__ Qout,
                                                  float* __restrict__ partial) {
    const int wid = threadIdx.x >> 6, lane = threadIdx.x & 63;
    const int l16 = lane & 15, lhi = lane >> 4;
    const int row0 = blockIdx.x * 64 + wid * 16;

    // A fragments (l rows, bf16) + per-row ||l||^2 in f32
    bf16x8 af[4];
    float sq = 0.f;
    const float* lrow = lout + (long)(row0 + l16) * DLAT;
    #pragma unroll
    for (int ks = 0; ks < 4; ++ks) {
        const float4* lp = (const float4*)(lrow + ks * 32 + lhi * 8);
        float4 v0 = lp[0], v1 = lp[1];
        sq += v0.x * v0.x + v0.y * v0.y + v0.z * v0.z + v0.w * v0.w
            + v1.x * v1.x + v1.y * v1.y + v1.z * v1.z + v1.w * v1.w;
        bf16x8 a;
        a[0] = f2bf(v0.x); a[1] = f2bf(v0.y); a[2] = f2bf(v0.z); a[3] = f2bf(v0.w);
        a[4] = f2bf(v1.x); a[5] = f2bf(v1.y); a[6] = f2bf(v1.z); a[7] = f2bf(v1.w);
        af[ks] = a;
    }
    sq += __shfl_xor(sq, 16, 64);
    sq += __shfl_xor(sq, 32, 64);          // lane L holds lsq of row (L&15)
    float lsqr[4];
    #pragma unroll
    for (int r = 0; r < 4; ++r) lsqr[r] = __shfl(sq, lhi * 4 + r, 64);

    f32x4 numv[32];
    float rsum[4] = {0.f, 0.f, 0.f, 0.f};
    #pragma unroll
    for (int nb = 0; nb < 32; ++nb) {
        f32x4 acc = (f32x4){0.f, 0.f, 0.f, 0.f};
        const short* cbase = cb + (nb * 16 + l16) * DLAT;
        #pragma unroll
        for (int ks = 0; ks < 4; ++ks) {
            const bf16x8 bf = *(const bf16x8*)(cbase + ks * 32 + lhi * 8);
            acc = __builtin_amdgcn_mfma_f32_16x16x32_bf16(af[ks], bf, acc, 0, 0, 0);
        }
        float cs = csq[nb * 16 + l16];
        f32x4 nm;
        #pragma unroll
        for (int r = 0; r < 4; ++r) {
            float Dv = lsqr[r] + cs - 2.f * acc[r];
            float v = 1.f / (1.f + Dv);    // alpha=1: (1+D)^(-1)
            nm[r] = v;
            rsum[r] += v;
        }
        numv[nb] = nm;
    }
    #pragma unroll
    for (int m = 1; m <= 8; m <<= 1) {
        #pragma unroll
        for (int r = 0; r < 4; ++r) rsum[r] += __shfl_xor(rsum[r], m, 64);
    }
    float inv[4];
    #pragma unroll
    for (int r = 0; r < 4; ++r) inv[r] = 1.f / rsum[r];

    __shared__ float lds_fq[4][KC];
    #pragma unroll
    for (int nb = 0; nb < 32; ++nb) {
        float cp = 0.f;
        #pragma unroll
        for (int r = 0; r < 4; ++r) {
            float q = numv[nb][r] * inv[r];
            Qout[(long)(row0 + lhi * 4 + r) * KC + nb * 16 + l16] = q;
            cp += q;
        }
        cp += __shfl_xor(cp, 16, 64);
        cp += __shfl_xor(cp, 32, 64);      // colsum over this wave's 16 rows
        if (lhi == 0) lds_fq[wid][nb * 16 + l16] = cp;
    }
    __syncthreads();
    for (int c = threadIdx.x; c < KC; c += 256) {
        partial[(long)blockIdx.x * KC + c] =
            lds_fq[0][c] + lds_fq[1][c] + lds_fq[2][c] + lds_fq[3][c];
    }
}

// ---------- K3: Fq[c] = sum over 1024 block partials (deterministic tree) ----------
__global__ __launch_bounds__(256) void fq_reduce(const float* __restrict__ partial,
                                                 float* __restrict__ fq) {
    int c = blockIdx.x;
    float s = 0.f;
    #pragma unroll
    for (int i = 0; i < 4; ++i) s += partial[(long)(threadIdx.x + i * 256) * KC + c];
    __shared__ float red[256];
    red[threadIdx.x] = s;
    __syncthreads();
    for (int off = 128; off >= 1; off >>= 1) {
        if (threadIdx.x < off) red[threadIdx.x] += red[threadIdx.x + off];
        __syncthreads();
    }
    if (threadIdx.x == 0) fq[c] = red[0];
}

// ---------- K4: P = rownorm(Q^2 / Fq) ----------
__global__ __launch_bounds__(256) void p_kernel(const float* __restrict__ Q,
                                                const float* __restrict__ fq,
                                                float* __restrict__ P) {
    const int wid = threadIdx.x >> 6, lane = threadIdx.x & 63;
    const int gw = blockIdx.x * 4 + wid;   // 0..8191 waves, each does 8 rows
    const float4 f0 = *(const float4*)(fq + lane * 8);
    const float4 f1 = *(const float4*)(fq + lane * 8 + 4);
    float inv[8] = {1.f / f0.x, 1.f / f0.y, 1.f / f0.z, 1.f / f0.w,
                    1.f / f1.x, 1.f / f1.y, 1.f / f1.z, 1.f / f1.w};
    for (int it = 0; it < 8; ++it) {
        const long row = gw + (long)it * 8192;
        const float4* qp = (const float4*)(Q + row * KC + lane * 8);
        float4 q0 = qp[0], q1 = qp[1];
        float n[8];
        n[0] = q0.x * q0.x * inv[0]; n[1] = q0.y * q0.y * inv[1];
        n[2] = q0.z * q0.z * inv[2]; n[3] = q0.w * q0.w * inv[3];
        n[4] = q1.x * q1.x * inv[4]; n[5] = q1.y * q1.y * inv[5];
        n[6] = q1.z * q1.z * inv[6]; n[7] = q1.w * q1.w * inv[7];
        float rs = n[0] + n[1] + n[2] + n[3] + n[4] + n[5] + n[6] + n[7];
        #pragma unroll
        for (int m = 1; m <= 32; m <<= 1) rs += __shfl_xor(rs, m, 64);
        float ir = 1.f / rs;
        float4 o0 = {n[0] * ir, n[1] * ir, n[2] * ir, n[3] * ir};
        float4 o1 = {n[4] * ir, n[5] * ir, n[6] * ir, n[7] * ir};
        float4* pp = (float4*)(P + row * KC + lane * 8);
        pp[0] = o0; pp[1] = o1;
    }
}

extern "C" void kernel_launch(void* const* d_in, const int* in_sizes, int n_in,
                              void* d_out, int out_size, void* d_ws, size_t ws_size,
                              hipStream_t stream) {
    const float* x  = (const float*)d_in[0];
    const float* W  = (const float*)d_in[1];
    const float* b  = (const float*)d_in[2];
    const float* C  = (const float*)d_in[3];

    float* out  = (float*)d_out;
    float* lout = out;                                   // 65536*128
    float* Qout = out + (long)NROWS * DLAT;              // 65536*512
    float* Pout = Qout + (long)NROWS * KC;               // 65536*512

    // workspace layout (needs ~2.44 MB)
    char*  ws      = (char*)d_ws;
    short* Wt      = (short*)ws;                         // 131072 * 2 B
    short* cb      = (short*)(ws + 262144);              // 65536 * 2 B
    float* csq     = (float*)(ws + 262144 + 131072);     // 512 * 4 B
    float* partial = (float*)(ws + 395264);              // 1024*512*4 = 2 MB
    float* fq      = (float*)(ws + 395264 + 2097152);    // 512 * 4 B

    hipLaunchKernelGGL(prep_convert, dim3(768),  dim3(256), 0, stream, W, C, Wt, cb);
    hipLaunchKernelGGL(prep_csq,     dim3(512),  dim3(64),  0, stream, C, csq);
    hipLaunchKernelGGL(gemm1,        dim3(1024), dim3(256), 0, stream, x, Wt, b, lout);
    hipLaunchKernelGGL(gemm2_q,      dim3(1024), dim3(256), 0, stream, lout, cb, csq, Qout, partial);
    hipLaunchKernelGGL(fq_reduce,    dim3(512),  dim3(256), 0, stream, partial, fq);
    hipLaunchKernelGGL(p_kernel,     dim3(2048), dim3(256), 0, stream, Qout, fq, Pout);
}